// Round 5
// baseline (474.828 us; speedup 1.0000x reference)
//
#include <hip/hip_runtime.h>

#define NN 4096
#define HID 512
#define NH 8
#define HD 64

typedef __attribute__((ext_vector_type(8))) short short8;
typedef __attribute__((ext_vector_type(4))) float f32x4;

__device__ __forceinline__ ushort f2bf(float f) {
    unsigned u = __float_as_uint(f);
    return (ushort)((u + 0x7FFFu + ((u >> 16) & 1u)) >> 16);   // RNE
}

// ---------------- Kernel A: QKV projection (f32 compute, bf16 output) -----------------
__global__ __launch_bounds__(256) void qkv_kernel(
    const float* __restrict__ x,
    const float* __restrict__ Wq, const float* __restrict__ bq,
    const float* __restrict__ Wk, const float* __restrict__ bk,
    const float* __restrict__ Wv, const float* __restrict__ bv,
    ushort* __restrict__ Qb, ushort* __restrict__ Kb, ushort* __restrict__ Vt)
{
    const int mat = blockIdx.z;
    const float* W = (mat == 0) ? Wq : ((mat == 1) ? Wk : Wv);
    const float* b = (mat == 0) ? bq : ((mat == 1) ? bk : bv);

    const int row0 = blockIdx.y * 128;
    const int col0 = blockIdx.x * 128;
    const int tid = threadIdx.x;
    const int tx = tid & 15, ty = tid >> 4;

    __shared__ float xs[32][132];
    __shared__ float wt[32][132];
    __shared__ __align__(16) ushort vts[128][136];

    float acc[8][8];
#pragma unroll
    for (int i = 0; i < 8; ++i)
#pragma unroll
        for (int j = 0; j < 8; ++j) acc[i][j] = 0.f;

    for (int kc = 0; kc < HID; kc += 32) {
#pragma unroll
        for (int it = 0; it < 4; ++it) {
            int f = it * 256 + tid;
            int i = f >> 3, k4 = f & 7;
            float4 v = *(const float4*)(x + (size_t)(row0 + i) * HID + kc + k4 * 4);
            xs[k4 * 4 + 0][i] = v.x; xs[k4 * 4 + 1][i] = v.y;
            xs[k4 * 4 + 2][i] = v.z; xs[k4 * 4 + 3][i] = v.w;
        }
#pragma unroll
        for (int it = 0; it < 4; ++it) {
            int f = it * 256 + tid;
            int k = f >> 5, c4 = f & 31;
            float4 v = *(const float4*)(W + (size_t)(kc + k) * HID + col0 + c4 * 4);
            *(float4*)&wt[k][c4 * 4] = v;
        }
        __syncthreads();
        for (int k = 0; k < 32; ++k) {
            float a0[8], b0[8];
            *(float4*)&a0[0] = *(const float4*)&xs[k][ty * 4];
            *(float4*)&a0[4] = *(const float4*)&xs[k][64 + ty * 4];
            *(float4*)&b0[0] = *(const float4*)&wt[k][tx * 4];
            *(float4*)&b0[4] = *(const float4*)&wt[k][64 + tx * 4];
#pragma unroll
            for (int i = 0; i < 8; ++i)
#pragma unroll
                for (int j = 0; j < 8; ++j)
                    acc[i][j] = fmaf(a0[i], b0[j], acc[i][j]);
        }
        __syncthreads();
    }

    if (mat < 2) {
        ushort* O = (mat == 0) ? Qb : Kb;
#pragma unroll
        for (int bi = 0; bi < 2; ++bi)
#pragma unroll
            for (int ii = 0; ii < 4; ++ii) {
                int r = row0 + bi * 64 + ty * 4 + ii;
#pragma unroll
                for (int bj = 0; bj < 2; ++bj) {
                    int c = col0 + bj * 64 + tx * 4;
                    ushort4 u;
                    u.x = f2bf(acc[bi * 4 + ii][bj * 4 + 0] + b[c + 0]);
                    u.y = f2bf(acc[bi * 4 + ii][bj * 4 + 1] + b[c + 1]);
                    u.z = f2bf(acc[bi * 4 + ii][bj * 4 + 2] + b[c + 2]);
                    u.w = f2bf(acc[bi * 4 + ii][bj * 4 + 3] + b[c + 3]);
                    *(ushort4*)(O + ((size_t)(c >> 6) * NN + r) * HD + (c & 63)) = u;
                }
            }
    } else {
#pragma unroll
        for (int bi = 0; bi < 2; ++bi)
#pragma unroll
            for (int ii = 0; ii < 4; ++ii) {
                int rl = bi * 64 + ty * 4 + ii;
#pragma unroll
                for (int bj = 0; bj < 2; ++bj)
#pragma unroll
                    for (int j = 0; j < 4; ++j) {
                        int cl = bj * 64 + tx * 4 + j;
                        vts[cl][rl] = f2bf(acc[bi * 4 + ii][bj * 4 + j] + b[col0 + cl]);
                    }
            }
        __syncthreads();
        int cl = tid >> 1, hf = tid & 1;
        const ushort* src = &vts[cl][hf * 64];
        ushort* dst = Vt + (size_t)(col0 + cl) * NN + row0 + hf * 64;
#pragma unroll
        for (int k = 0; k < 8; ++k)
            *(uint4*)(dst + k * 8) = *(const uint4*)(src + k * 8);
    }
}

// ---------------- fused attention helpers ----------------
__device__ __forceinline__ void prefk(short8 (&K)[8], const ushort* __restrict__ Kh,
                                      int bb, int li, int g) {
#pragma unroll
    for (int jj = 0; jj < 4; ++jj) {
        const ushort* kp = Kh + (size_t)(bb + jj * 16 + li) * HD + g * 8;
        K[jj * 2 + 0] = *(const short8*)kp;
        K[jj * 2 + 1] = *(const short8*)(kp + 32);
    }
}

__device__ __forceinline__ void bodyA(const short8 (&K)[8], short8 qa0, short8 qa1,
                                      float& zsum) {
#pragma unroll
    for (int jj = 0; jj < 4; ++jj) {
        f32x4 acc = {0.f, 0.f, 0.f, 0.f};
        acc = __builtin_amdgcn_mfma_f32_16x16x32_bf16(K[jj * 2 + 0], qa0, acc, 0, 0, 0);
        acc = __builtin_amdgcn_mfma_f32_16x16x32_bf16(K[jj * 2 + 1], qa1, acc, 0, 0, 0);
#pragma unroll
        for (int r = 0; r < 4; ++r) zsum += __expf(acc[r] * 0.125f);
    }
}

__device__ __forceinline__ void bodyB(const short8 (&K)[8],
                                      const ushort* __restrict__ Vh,
                                      short8 qa0, short8 qa1, float iz,
                                      float* __restrict__ WH, char* __restrict__ myp,
                                      f32x4 (&pv)[4],
                                      int bb, int row0, int li, int g) {
    // V loads for THIS chunk issued first (before this chunk's stores).
    short8 V[8];
#pragma unroll
    for (int t = 0; t < 8; ++t) {
        int kb2 = t >> 2, dt = t & 3;
        V[t] = *(const short8*)(Vh + bb + kb2 * 32 + g * 8 + (size_t)(dt * 16 + li) * NN);
    }
    // QK^T + exp + weight store + P pack
#pragma unroll
    for (int jj = 0; jj < 4; ++jj) {
        f32x4 acc = {0.f, 0.f, 0.f, 0.f};
        acc = __builtin_amdgcn_mfma_f32_16x16x32_bf16(K[jj * 2 + 0], qa0, acc, 0, 0, 0);
        acc = __builtin_amdgcn_mfma_f32_16x16x32_bf16(K[jj * 2 + 1], qa1, acc, 0, 0, 0);
        f32x4 ev;
#pragma unroll
        for (int r = 0; r < 4; ++r) ev[r] = __expf(acc[r] * 0.125f) * iz;
        __builtin_nontemporal_store(ev,
            (f32x4*)(WH + (size_t)(row0 + li) * NN + bb + jj * 16 + g * 4));
        uint pk0 = (uint)f2bf(ev[0]) | ((uint)f2bf(ev[1]) << 16);
        uint pk1 = (uint)f2bf(ev[2]) | ((uint)f2bf(ev[3]) << 16);
        int boff = (li * 128 + jj * 32 + g * 8) ^ ((li & 7) << 4);
        *(uint2*)(myp + boff) = make_uint2(pk0, pk1);
    }
    // PV from LDS P + V regs
#pragma unroll
    for (int kb2 = 0; kb2 < 2; ++kb2) {
        int rb = (li * 128 + kb2 * 64 + g * 16) ^ ((li & 7) << 4);
        short8 pa = *(const short8*)(myp + rb);
#pragma unroll
        for (int dt = 0; dt < 4; ++dt)
            pv[dt] = __builtin_amdgcn_mfma_f32_16x16x32_bf16(pa, V[kb2 * 4 + dt], pv[dt], 0, 0, 0);
    }
}

// ---------------- Kernel B: fused attention ----------------
// grid (256, 8), block 256 (4 waves). 16 q-rows/block, wave-sliced k (1024 each).
// Swapped MFMA (D = S^T): lane (g,li) holds q=li, k=bb+jj*16+g*4+r.
// K double-buffered in regs (prefetch next chunk BEFORE this chunk's stores) so
// vmcnt waits for loads never drain the weight-store backlog.
__global__ __launch_bounds__(256) void attn_kernel(
    const ushort* __restrict__ Qb, const ushort* __restrict__ Kb,
    const ushort* __restrict__ Vt,
    float* __restrict__ wout, float* __restrict__ att)
{
    const int h = blockIdx.y;
    const int row0 = blockIdx.x * 16;
    const int tid = threadIdx.x;
    const int w = tid >> 6, lane = tid & 63;
    const int g = lane >> 4, li = lane & 15;

    const ushort* Qh = Qb + (size_t)h * NN * HD;
    const ushort* Kh = Kb + (size_t)h * NN * HD;
    const ushort* Vh = Vt + (size_t)h * HD * NN;
    float* WH = wout + ((size_t)h << 24);

    // per-wave 4352B region: bf16 P tile (2KB, XOR-swizzled) during the loop;
    // attred f32[16][68] overlay afterwards.
    __shared__ __align__(16) char smem[4 * 4352];
    __shared__ float zpart[4][16];
    char* myp = smem + w * 4352;

    const short8 qa0 = *(const short8*)(Qh + (size_t)(row0 + li) * HD + g * 8);
    const short8 qa1 = *(const short8*)(Qh + (size_t)(row0 + li) * HD + 32 + g * 8);

    const int k0 = w * 1024;    // this wave's k-slice

    short8 kA[8], kB[8];

    // ---- Pass A: Z over this wave's k-slice (double-buffered) ----
    float zsum = 0.f;
    prefk(kA, Kh, k0, li, g);
    for (int c = 0; c < 16; c += 2) {
        prefk(kB, Kh, k0 + (c + 1) * 64, li, g);
        bodyA(kA, qa0, qa1, zsum);
        if (c + 2 < 16) prefk(kA, Kh, k0 + (c + 2) * 64, li, g);
        bodyA(kB, qa0, qa1, zsum);
    }
    zsum += __shfl_xor(zsum, 16);
    zsum += __shfl_xor(zsum, 32);
    if (lane < 16) zpart[w][li] = zsum;
    __syncthreads();
    const float iz = 1.0f / (zpart[0][li] + zpart[1][li] + zpart[2][li] + zpart[3][li]);

    // ---- Pass B: weights + P@V (K double-buffered, stores decoupled) ----
    f32x4 pv[4];
#pragma unroll
    for (int dt = 0; dt < 4; ++dt) pv[dt] = (f32x4){0.f, 0.f, 0.f, 0.f};

    prefk(kA, Kh, k0, li, g);
    for (int c = 0; c < 16; c += 2) {
        prefk(kB, Kh, k0 + (c + 1) * 64, li, g);
        bodyB(kA, Vh, qa0, qa1, iz, WH, myp, pv, k0 + c * 64, row0, li, g);
        if (c + 2 < 16) prefk(kA, Kh, k0 + (c + 2) * 64, li, g);
        bodyB(kB, Vh, qa0, qa1, iz, WH, myp, pv, k0 + (c + 1) * 64, row0, li, g);
    }

    // ---- cross-wave PV reduction (attred overlays P staging) ----
    float* arw = (float*)myp;
#pragma unroll
    for (int dt = 0; dt < 4; ++dt)
#pragma unroll
        for (int r = 0; r < 4; ++r)
            arw[(g * 4 + r) * 68 + dt * 16 + li] = pv[dt][r];
    __syncthreads();

    {
        int q = tid >> 4;
        int d0 = (tid & 15) * 4;
        f32x4 s = *(const f32x4*)((const float*)(smem + 0 * 4352) + q * 68 + d0);
        s += *(const f32x4*)((const float*)(smem + 1 * 4352) + q * 68 + d0);
        s += *(const f32x4*)((const float*)(smem + 2 * 4352) + q * 68 + d0);
        s += *(const f32x4*)((const float*)(smem + 3 * 4352) + q * 68 + d0);
        *(f32x4*)(att + (size_t)(row0 + q) * HID + h * HD + d0) = s;
    }
}

// ---------------- Kernel C: output = att @ Wo + bo ----------------
__global__ __launch_bounds__(256) void out_kernel(
    const float* __restrict__ att, const float* __restrict__ Wo,
    const float* __restrict__ bo, float* __restrict__ outp)
{
    const int row0 = blockIdx.x * 64;
    const int tid = threadIdx.x;
    const int tx = tid & 15, ty = tid >> 4;

    __shared__ float as_[64][68];
    __shared__ float ws2[64][68];

    float acc[4][4];
#pragma unroll
    for (int i = 0; i < 4; ++i)
#pragma unroll
        for (int j = 0; j < 4; ++j) acc[i][j] = 0.f;

    for (int kc = 0; kc < HID; kc += 64) {
#pragma unroll
        for (int it = 0; it < 4; ++it) {
            int f = it * 256 + tid;
            int i = f >> 4, k4 = f & 15;
            float4 v = *(const float4*)(att + (size_t)(row0 + i) * HID + kc + k4 * 4);
            as_[k4 * 4 + 0][i] = v.x; as_[k4 * 4 + 1][i] = v.y;
            as_[k4 * 4 + 2][i] = v.z; as_[k4 * 4 + 3][i] = v.w;
        }
#pragma unroll
        for (int it = 0; it < 4; ++it) {
            int f = it * 256 + tid;
            int k = f >> 4, c4 = f & 15;
            float4 v = *(const float4*)(Wo + (size_t)(kc + k) * HD + c4 * 4);
            *(float4*)&ws2[k][c4 * 4] = v;
        }
        __syncthreads();
        for (int k = 0; k < 64; ++k) {
            float a0[4], b0[4];
            *(float4*)&a0[0] = *(const float4*)&as_[k][ty * 4];
            *(float4*)&b0[0] = *(const float4*)&ws2[k][tx * 4];
#pragma unroll
            for (int i = 0; i < 4; ++i)
#pragma unroll
                for (int j = 0; j < 4; ++j)
                    acc[i][j] = fmaf(a0[i], b0[j], acc[i][j]);
        }
        __syncthreads();
    }

#pragma unroll
    for (int ii = 0; ii < 4; ++ii) {
        int r = row0 + ty * 4 + ii;
        float4 v;
        v.x = acc[ii][0] + bo[tx * 4 + 0];
        v.y = acc[ii][1] + bo[tx * 4 + 1];
        v.z = acc[ii][2] + bo[tx * 4 + 2];
        v.w = acc[ii][3] + bo[tx * 4 + 3];
        *(float4*)(outp + (size_t)r * HD + tx * 4) = v;
    }
}

extern "C" void kernel_launch(void* const* d_in, const int* in_sizes, int n_in,
                              void* d_out, int out_size, void* d_ws, size_t ws_size,
                              hipStream_t stream) {
    const float* x  = (const float*)d_in[0];
    const float* Wq = (const float*)d_in[1];
    const float* bq = (const float*)d_in[2];
    const float* Wk = (const float*)d_in[3];
    const float* bk = (const float*)d_in[4];
    const float* Wv = (const float*)d_in[5];
    const float* bv = (const float*)d_in[6];
    const float* Wo = (const float*)d_in[7];
    const float* bo = (const float*)d_in[8];

    float* out  = (float*)d_out;
    float* wout = out + (size_t)NN * HD;

    char* wsb = (char*)d_ws;
    ushort* Qb = (ushort*)wsb;
    ushort* Kb = Qb + (size_t)NH * NN * HD;
    ushort* Vt = Kb + (size_t)NH * NN * HD;
    float*  att = (float*)(wsb + 12u * 1024u * 1024u);

    hipLaunchKernelGGL(qkv_kernel, dim3(4, 32, 3), dim3(256), 0, stream,
                       x, Wq, bq, Wk, bk, Wv, bv, Qb, Kb, Vt);
    hipLaunchKernelGGL(attn_kernel, dim3(256, NH), dim3(256), 0, stream,
                       Qb, Kb, Vt, wout, att);
    hipLaunchKernelGGL(out_kernel, dim3(64), dim3(256), 0, stream,
                       att, Wo, bo, out);
}